// Round 1
// baseline (7802.872 us; speedup 1.0000x reference)
//
#include <hip/hip_runtime.h>
#include <cstdint>
#include <cstring>
#include <cmath>
#include <complex>
#include <vector>
#include <algorithm>

#define NEDGE 65536
#define NNODE 4096
#define FDIM  64
#define LMDIM 16
#define NPATHS 23
#define HDIM  64
#define NSPEC 10
#define MAXCG 1024
#define NF16  ((size_t)NNODE * FDIM * LMDIM)   // 4,194,304 floats

struct CGOff { int o[17]; };

// ---------------------------------------------------------------------------
// Device kernels
// ---------------------------------------------------------------------------

__global__ void mace_geom_kernel(const float* __restrict__ vec,
                                 float* __restrict__ ysh, float* __restrict__ rbf)
{
    int e = blockIdx.x * blockDim.x + threadIdx.x;
    if (e >= NEDGE) return;
    float x = vec[3*e+0], y = vec[3*e+1], z = vec[3*e+2];
    float r = sqrtf(x*x + y*y + z*z);
    float inv = 1.0f / (r + 1e-9f);
    float ux = x*inv, uy = y*inv, uz = z*inv;

    const float s3    = 1.7320508075688772f;
    const float s5_2  = 1.1180339887498949f;
    const float s15   = 3.8729833462074170f;
    const float s15_2 = 1.9364916731037085f;
    const float s35_8 = 2.0916500663351889f;
    const float s105  = 10.246950765959598f;
    const float s21_8 = 1.6201851746019651f;
    const float s7_2  = 1.3228756555322954f;
    const float s105_2= 5.1234753829797990f;

    float* Y = ysh + (size_t)e * 16;
    Y[0]  = 1.0f;
    Y[1]  = s3 * uy;
    Y[2]  = s3 * uz;
    Y[3]  = s3 * ux;
    Y[4]  = s15 * ux * uy;
    Y[5]  = s15 * uy * uz;
    Y[6]  = s5_2 * (3.f*uz*uz - 1.f);
    Y[7]  = s15 * ux * uz;
    Y[8]  = s15_2 * (ux*ux - uy*uy);
    Y[9]  = s35_8 * uy * (3.f*ux*ux - uy*uy);
    Y[10] = s105 * ux * uy * uz;
    Y[11] = s21_8 * uy * (5.f*uz*uz - 1.f);
    Y[12] = s7_2 * uz * (5.f*uz*uz - 3.f);
    Y[13] = s21_8 * ux * (5.f*uz*uz - 1.f);
    Y[14] = s105_2 * uz * (ux*ux - uy*uy);
    Y[15] = s35_8 * ux * (ux*ux - 3.f*uy*uy);

    float env = 0.f;
    if (r < 1.f) {
        float r2 = r*r, r3 = r2*r, r6 = r3*r3, r7 = r6*r, r8 = r7*r;
        env = 1.f - 28.f*r6 + 48.f*r7 - 21.f*r8;
    }
    const float sq2 = 1.4142135623730951f;
    const float PI_ = 3.14159265358979323846f;
    float* R = rbf + (size_t)e * 8;
    #pragma unroll
    for (int n = 1; n <= 8; n++)
        R[n-1] = sq2 * sinf(PI_ * (float)n * r) * inv * env;
}

__global__ void mace_init_h_kernel(const int* __restrict__ spec,
                                   const float* __restrict__ embed,
                                   float* __restrict__ h)
{
    int idx = blockIdx.x * blockDim.x + threadIdx.x;   // NNODE*1024
    int n = idx >> 10;
    int t = idx & 1023;
    int f = t >> 4, m = t & 15;
    h[idx] = (m == 0) ? embed[spec[n]*FDIM + f] : 0.f;
}

__global__ void mace_radial_kernel(const float* __restrict__ rbf,
                                   const float* __restrict__ W1,   // 8 x 64 (layer slice)
                                   float* __restrict__ hid)
{
    int idx = blockIdx.x * blockDim.x + threadIdx.x;   // NEDGE*64
    int e = idx >> 6, j = idx & 63;
    float a = 0.f;
    #pragma unroll
    for (int n = 0; n < 8; n++)
        a = fmaf(rbf[(size_t)e*8 + n], W1[n*64 + j], a);
    hid[idx] = a / (1.f + expf(-a));   // silu
}

// out[n,f,m] = scale * sum_g W[l(m),f,g] * in[n,g,m]  (+ add)
__global__ void mace_lin_kernel(const float* __restrict__ in,
                                const float* __restrict__ W,
                                const float* __restrict__ add,
                                float* __restrict__ out, float scale)
{
    int n = blockIdx.x;
    int tid = threadIdx.x;                 // 1024 = f*16+m
    __shared__ float s[1024];
    size_t base = (size_t)n * 1024;
    s[tid] = in[base + tid];
    __syncthreads();
    int f = tid >> 4, m = tid & 15;
    int l = (m == 0) ? 0 : (m < 4) ? 1 : (m < 9) ? 2 : 3;
    const float* w = W + l*4096 + f*64;
    float a = 0.f;
    #pragma unroll
    for (int g = 0; g < 64; g++)
        a = fmaf(w[g], s[g*16 + m], a);
    a *= scale;
    if (add) a += add[base + tid];
    out[base + tid] = a;
}

// species-indexed lin: W base + spec[n]*4*64*64
__global__ void mace_lin_sp_kernel(const float* __restrict__ in,
                                   const float* __restrict__ Wsp,
                                   const int* __restrict__ spec,
                                   float* __restrict__ out)
{
    int n = blockIdx.x;
    int tid = threadIdx.x;
    __shared__ float s[1024];
    size_t base = (size_t)n * 1024;
    s[tid] = in[base + tid];
    __syncthreads();
    int f = tid >> 4, m = tid & 15;
    int l = (m == 0) ? 0 : (m < 4) ? 1 : (m < 9) ? 2 : 3;
    const float* w = Wsp + (size_t)spec[n]*4*4096 + l*4096 + f*64;
    float a = 0.f;
    #pragma unroll
    for (int g = 0; g < 64; g++)
        a = fmaf(w[g], s[g*16 + m], a);
    out[base + tid] = a;
}

// Message pass: one block (64 threads = lanes f) per edge.
__global__ void mace_msg_kernel(const float* __restrict__ h1,    // N*F*16
                                const float* __restrict__ ysh,   // E*16
                                const float* __restrict__ hid,   // E*64
                                const float* __restrict__ W2,    // 64 x (23*64), layer slice
                                const int* __restrict__ senders,
                                const int* __restrict__ receivers,
                                const uint32_t* __restrict__ cg_pk,
                                const float* __restrict__ cg_c,
                                CGOff O,
                                float* __restrict__ out)         // N*F*16, atomics
{
    int e = blockIdx.x;
    int f = threadIdx.x;
    __shared__ float sy[16];
    __shared__ float shid[64];
    __shared__ float shv[64*17];
    __shared__ float srw[64*NPATHS];

    shid[f] = hid[(size_t)e*64 + f];
    if (f < 16) sy[f] = ysh[(size_t)e*16 + f];
    int s = senders[e];
    const float* hp = h1 + (size_t)s*1024 + f*16;
    #pragma unroll
    for (int k = 0; k < 16; k++) shv[f*17 + k] = hp[k];
    __syncthreads();

    // Rw[p] = sum_h hid[h] * W2[h*1472 + p*64 + f]
    float rw[NPATHS];
    #pragma unroll
    for (int p = 0; p < NPATHS; p++) rw[p] = 0.f;
    for (int h = 0; h < 64; h++) {
        float hh = shid[h];
        const float* w = W2 + (size_t)h*(NPATHS*64) + f;
        #pragma unroll
        for (int p = 0; p < NPATHS; p++)
            rw[p] = fmaf(hh, w[p*64], rw[p]);
    }
    #pragma unroll
    for (int p = 0; p < NPATHS; p++) srw[f*NPATHS + p] = rw[p];

    int r = receivers[e];
    float* dst = out + (size_t)r*1024 + f*16;
    #pragma unroll
    for (int k = 0; k < 16; k++) {
        float a = 0.f;
        int t0 = O.o[k], t1 = O.o[k+1];
        for (int t = t0; t < t1; t++) {
            uint32_t pk = cg_pk[t];
            int i = pk & 255, j = (pk >> 8) & 255, p = (pk >> 16) & 255;
            a = fmaf(cg_c[t], shv[f*17 + i] * sy[j] * srw[f*NPATHS + p], a);
        }
        atomicAdd(dst + k, a);
    }
}

// B2[n,f,k] = sum entries c * A[i] * A[j] * w2[p]
__global__ void mace_b2_kernel(const float* __restrict__ A,
                               const float* __restrict__ w2base,  // S x 23 x 64 (layer slice)
                               const int* __restrict__ spec,
                               const uint32_t* __restrict__ cg_pk,
                               const float* __restrict__ cg_c,
                               CGOff O,
                               float* __restrict__ B2)
{
    int n = blockIdx.x;
    int f = threadIdx.x;
    __shared__ float sA[64*17];
    __shared__ float sw[64*NPATHS];
    const float* ap = A + (size_t)n*1024 + f*16;
    #pragma unroll
    for (int k = 0; k < 16; k++) sA[f*17 + k] = ap[k];
    int sp = spec[n];
    const float* w2 = w2base + (size_t)sp*(NPATHS*64) + f;
    #pragma unroll
    for (int p = 0; p < NPATHS; p++) sw[f*NPATHS + p] = w2[p*64];

    float* out = B2 + (size_t)n*1024 + f*16;
    #pragma unroll
    for (int k = 0; k < 16; k++) {
        float a = 0.f;
        int t0 = O.o[k], t1 = O.o[k+1];
        for (int t = t0; t < t1; t++) {
            uint32_t pk = cg_pk[t];
            int i = pk & 255, j = (pk >> 8) & 255, p = (pk >> 16) & 255;
            a = fmaf(cg_c[t], sA[f*17 + i] * sA[f*17 + j] * sw[f*NPATHS + p], a);
        }
        out[k] = a;
    }
}

// out = A*w1 + B2 + B3 where B3[k] = sum entries c * B2[i] * A[j] * w3[p]
__global__ void mace_b3_kernel(const float* __restrict__ A,
                               const float* __restrict__ B2,
                               const float* __restrict__ w3base,  // S x 23 x 64 (layer slice)
                               const float* __restrict__ w1base,  // S x 64   (layer slice)
                               const int* __restrict__ spec,
                               const uint32_t* __restrict__ cg_pk,
                               const float* __restrict__ cg_c,
                               CGOff O,
                               float* __restrict__ out)
{
    int n = blockIdx.x;
    int f = threadIdx.x;
    __shared__ float sA[64*17];
    __shared__ float sB[64*17];
    __shared__ float sw[64*NPATHS];
    const float* ap = A  + (size_t)n*1024 + f*16;
    const float* bp = B2 + (size_t)n*1024 + f*16;
    #pragma unroll
    for (int k = 0; k < 16; k++) { sA[f*17 + k] = ap[k]; sB[f*17 + k] = bp[k]; }
    int sp = spec[n];
    const float* w3 = w3base + (size_t)sp*(NPATHS*64) + f;
    #pragma unroll
    for (int p = 0; p < NPATHS; p++) sw[f*NPATHS + p] = w3[p*64];
    float w1 = w1base[sp*64 + f];

    float* op = out + (size_t)n*1024 + f*16;
    #pragma unroll
    for (int k = 0; k < 16; k++) {
        float a = 0.f;
        int t0 = O.o[k], t1 = O.o[k+1];
        for (int t = t0; t < t1; t++) {
            uint32_t pk = cg_pk[t];
            int i = pk & 255, j = (pk >> 8) & 255, p = (pk >> 16) & 255;
            a = fmaf(cg_c[t], sB[f*17 + i] * sA[f*17 + j] * sw[f*NPATHS + p], a);
        }
        op[k] = sA[f*17 + k] * w1 + sB[f*17 + k] + a;
    }
}

__global__ void mace_readout0_kernel(const float* __restrict__ h,
                                     const float* __restrict__ roW,
                                     float* __restrict__ out)
{
    int n = blockIdx.x;
    int f = threadIdx.x;   // 64
    float v = h[(size_t)n*1024 + f*16] * roW[f];
    #pragma unroll
    for (int o = 32; o > 0; o >>= 1) v += __shfl_down(v, o, 64);
    if (f == 0) out[n] = v;   // assign (first contribution)
}

__global__ void mace_readout1_kernel(const float* __restrict__ h,
                                     const float* __restrict__ W1,  // 64x16
                                     const float* __restrict__ W2,  // 16
                                     float* __restrict__ out)
{
    int n = blockIdx.x;
    int f = threadIdx.x;   // 64
    __shared__ float sx[64];
    __shared__ float sz[16];
    sx[f] = h[(size_t)n*1024 + f*16];
    __syncthreads();
    if (f < 16) {
        float z = 0.f;
        #pragma unroll
        for (int g = 0; g < 64; g++) z = fmaf(sx[g], W1[g*16 + f], z);
        z = z / (1.f + expf(-z));    // silu
        sz[f] = z * W2[f];
    }
    __syncthreads();
    if (f == 0) {
        float t = 0.f;
        #pragma unroll
        for (int j = 0; j < 16; j++) t += sz[j];
        out[n] += t;
    }
}

// ---------------------------------------------------------------------------
// Host-side CG table construction (double precision, mirrors the reference)
// ---------------------------------------------------------------------------

struct HostCG {
    std::vector<uint32_t> upload;  // [MAXCG packed][MAXCG float-bits]
    CGOff off;
    int ncg;
};

static double fct_(int n) { double r = 1.0; for (int i = 2; i <= n; i++) r *= i; return r; }

static double su2_cg_(int j1, int j2, int j3, int m1, int m2, int m3)
{
    if (m1 + m2 != m3) return 0.0;
    int vmin = std::max(std::max(-j1 + j2 + m3, -j1 + m1), 0);
    int vmax = std::min(std::min(j2 + j3 + m1, j3 - j1 + j2), j3 + m3);
    double C = std::sqrt((2.0*j3 + 1.0) * fct_(j3 + j1 - j2) * fct_(j3 - j1 + j2) * fct_(j1 + j2 - j3) / fct_(j1 + j2 + j3 + 1))
             * std::sqrt(fct_(j3 + m3) * fct_(j3 - m3) / (fct_(j1 - m1) * fct_(j1 + m1) * fct_(j2 - m2) * fct_(j2 + m2)));
    double S = 0.0;
    for (int v = vmin; v <= vmax; v++) {
        double t = fct_(j2 + j3 + m1 - v) * fct_(j1 - m1 + v)
                 / (fct_(v) * fct_(j3 - j1 + j2 - v) * fct_(j3 + m3 - v) * fct_(v + j1 - j2 - m3));
        S += (((v + j2 + m2) & 1) ? -1.0 : 1.0) * t;
    }
    return C * S;
}

typedef std::complex<double> cdbl;

static void qmat_(int l, cdbl q[7][7])
{
    for (int a = 0; a < 7; a++) for (int b = 0; b < 7; b++) q[a][b] = cdbl(0, 0);
    double is2 = 1.0 / std::sqrt(2.0);
    for (int m = -l; m < 0; m++) {
        q[l + m][l - m] = cdbl(is2, 0);     // column l+|m|
        q[l + m][l + m] = cdbl(0, -is2);    // column l-|m|
    }
    q[l][l] = cdbl(1, 0);
    for (int m = 1; m <= l; m++) {
        double s = (m & 1) ? -1.0 : 1.0;
        q[l + m][l + m] = cdbl(s * is2, 0);
        q[l + m][l - m] = cdbl(0, s * is2);
    }
    cdbl ph = (l == 0) ? cdbl(1, 0) : (l == 1) ? cdbl(0, -1) : (l == 2) ? cdbl(-1, 0) : cdbl(0, 1);
    for (int a = 0; a < 7; a++) for (int b = 0; b < 7; b++) q[a][b] *= ph;
}

static HostCG build_cg_()
{
    std::vector<uint32_t> pk_k[16];
    std::vector<float>    c_k[16];
    int pidx = 0;
    for (int l1 = 0; l1 <= 3; l1++)
    for (int l2 = 0; l2 <= 3; l2++)
    for (int l3 = std::abs(l1 - l2); l3 <= std::min(3, l1 + l2); l3++) {
        if ((l1 + l2 + l3) & 1) continue;
        int d1 = 2*l1 + 1, d2 = 2*l2 + 1, d3 = 2*l3 + 1;
        cdbl q1[7][7], q2[7][7], q3[7][7];
        qmat_(l1, q1); qmat_(l2, q2); qmat_(l3, q3);
        double Cc[7][7][7];
        for (int i = 0; i < d1; i++)
        for (int k = 0; k < d2; k++)
        for (int m = 0; m < d3; m++)
            Cc[i][k][m] = su2_cg_(l1, l2, l3, i - l1, k - l2, m - l3);
        // C[j,b,c] = sum_{i,k,m} q1[i][j] q2[k][b] conj(q3[m][c]) Cc[i][k][m]
        for (int j = 0; j < d1; j++)
        for (int b = 0; b < d2; b++)
        for (int c = 0; c < d3; c++) {
            cdbl s(0, 0);
            for (int i = 0; i < d1; i++)
            for (int k = 0; k < d2; k++)
            for (int m = 0; m < d3; m++)
                s += q1[i][j] * q2[k][b] * std::conj(q3[m][c]) * Cc[i][k][m];
            float v = (float)s.real();
            if (std::fabs(v) > 1e-10f) {
                int kg = l3*l3 + c;
                pk_k[kg].push_back((uint32_t)(l1*l1 + j) | ((uint32_t)(l2*l2 + b) << 8) | ((uint32_t)pidx << 16));
                c_k[kg].push_back(v);
            }
        }
        pidx++;
    }
    HostCG T;
    T.upload.assign(2 * MAXCG, 0u);
    int pos = 0;
    for (int k = 0; k < 16; k++) {
        T.off.o[k] = pos;
        for (size_t t = 0; t < pk_k[k].size() && pos < MAXCG; t++) {
            T.upload[pos] = pk_k[k][t];
            uint32_t bits;
            float cv = c_k[k][t];
            std::memcpy(&bits, &cv, 4);
            T.upload[MAXCG + pos] = bits;
            pos++;
        }
    }
    T.off.o[16] = pos;
    T.ncg = pos;
    return T;
}

// ---------------------------------------------------------------------------
// kernel_launch
// ---------------------------------------------------------------------------

extern "C" void kernel_launch(void* const* d_in, const int* in_sizes, int n_in,
                              void* d_out, int out_size, void* d_ws, size_t ws_size,
                              hipStream_t stream)
{
    const float* vectors = (const float*)d_in[0];
    const int*   senders = (const int*)d_in[1];
    const int*   receivers = (const int*)d_in[2];
    const int*   spec    = (const int*)d_in[3];
    const float* embed_W = (const float*)d_in[4];
    const float* skip_W  = (const float*)d_in[5];
    const float* lin1_W  = (const float*)d_in[6];
    const float* radW1   = (const float*)d_in[7];
    const float* radW2   = (const float*)d_in[8];
    const float* lin2_W  = (const float*)d_in[9];
    const float* skipf_W = (const float*)d_in[10];
    const float* prodW1  = (const float*)d_in[11];
    const float* prodW2  = (const float*)d_in[12];
    const float* prodW3  = (const float*)d_in[13];
    const float* plin_W  = (const float*)d_in[14];
    const float* ro_W    = (const float*)d_in[15];
    const float* mlp_W1  = (const float*)d_in[16];
    const float* mlp_W2  = (const float*)d_in[17];
    float* out = (float*)d_out;

    // workspace layout (floats)
    float* w   = (float*)d_ws;
    float* ysh = w;                              // E*16
    float* rbf = ysh + (size_t)NEDGE * 16;       // E*8
    float* h   = rbf + (size_t)NEDGE * 8;        // N*F*16
    float* t0  = h  + NF16;
    float* t1  = t0 + NF16;
    float* t2  = t1 + NF16;
    float* t3  = t2 + NF16;                      // doubles as hid (E*64 == N*F*16)
    float* sc  = t3 + NF16;
    uint32_t* d_cgpk = (uint32_t*)(sc + NF16);
    float*    d_cgc  = (float*)(d_cgpk + MAXCG);

    static HostCG T = build_cg_();
    hipMemcpyAsync(d_cgpk, T.upload.data(), T.upload.size() * sizeof(uint32_t),
                   hipMemcpyHostToDevice, stream);

    const float EPS = 0.24253562503633297f;   // 1/sqrt(1+16)

    mace_geom_kernel<<<NEDGE/256, 256, 0, stream>>>(vectors, ysh, rbf);
    mace_init_h_kernel<<<(NNODE*1024)/256, 256, 0, stream>>>(spec, embed_W, h);

    for (int layer = 0; layer < 2; layer++) {
        const float* W1 = radW1 + (size_t)layer * 8 * HDIM;
        const float* W2 = radW2 + (size_t)layer * HDIM * NPATHS * FDIM;
        const float* l1W = lin1_W + (size_t)layer * 4 * FDIM * FDIM;
        const float* l2W = lin2_W + (size_t)layer * 4 * FDIM * FDIM;
        const float* plW = plin_W + (size_t)layer * 4 * FDIM * FDIM;
        const float* pw1 = prodW1 + (size_t)layer * NSPEC * FDIM;
        const float* pw2 = prodW2 + (size_t)layer * NSPEC * NPATHS * FDIM;
        const float* pw3 = prodW3 + (size_t)layer * NSPEC * NPATHS * FDIM;

        if (layer == 1) {
            // sc from h at start of iteration
            mace_lin_sp_kernel<<<NNODE, 1024, 0, stream>>>(
                h, skip_W + (size_t)1 * NSPEC * 4 * FDIM * FDIM, spec, sc);
        }

        mace_radial_kernel<<<(NEDGE*HDIM)/256, 256, 0, stream>>>(rbf, W1, t3);
        mace_lin_kernel<<<NNODE, 1024, 0, stream>>>(h, l1W, nullptr, t0, 1.0f);
        hipMemsetAsync(t1, 0, NF16 * sizeof(float), stream);
        mace_msg_kernel<<<NEDGE, 64, 0, stream>>>(t0, ysh, t3, W2, senders, receivers,
                                                  d_cgpk, d_cgc, T.off, t1);
        mace_lin_kernel<<<NNODE, 1024, 0, stream>>>(t1, l2W, nullptr, t2, EPS);

        if (layer == 0) {
            mace_lin_sp_kernel<<<NNODE, 1024, 0, stream>>>(t2, skipf_W, spec, h);
            // A = h
            mace_b2_kernel<<<NNODE, 64, 0, stream>>>(h, pw2, spec, d_cgpk, d_cgc, T.off, t2);
            mace_b3_kernel<<<NNODE, 64, 0, stream>>>(h, t2, pw3, pw1, spec, d_cgpk, d_cgc, T.off, t1);
            mace_lin_kernel<<<NNODE, 1024, 0, stream>>>(t1, plW, nullptr, h, 1.0f);
            mace_readout0_kernel<<<NNODE, 64, 0, stream>>>(h, ro_W, out);
        } else {
            // A = t2
            mace_b2_kernel<<<NNODE, 64, 0, stream>>>(t2, pw2, spec, d_cgpk, d_cgc, T.off, h);
            mace_b3_kernel<<<NNODE, 64, 0, stream>>>(t2, h, pw3, pw1, spec, d_cgpk, d_cgc, T.off, t1);
            mace_lin_kernel<<<NNODE, 1024, 0, stream>>>(t1, plW, sc, t0, 1.0f);
            mace_readout1_kernel<<<NNODE, 64, 0, stream>>>(t0, mlp_W1, mlp_W2, out);
        }
    }
}

// Round 4
// 5276.775 us; speedup vs baseline: 1.4787x; 1.4787x over previous
//
#include <hip/hip_runtime.h>
#include <cstdint>
#include <cstring>
#include <cmath>
#include <complex>
#include <vector>
#include <algorithm>

#define NEDGE 65536
#define NNODE 4096
#define FDIM  64
#define LMDIM 16
#define NPATHS 23
#define HDIM  64
#define NSPEC 10
#define MAXCG 1024
#define RWN   (NPATHS*FDIM)                    // 1472
#define NF16  ((size_t)NNODE * FDIM * LMDIM)   // 4,194,304 floats
#define W2RN  (64*6*64*4)                      // repacked W2: [h][g][f][q] = 98304 floats

struct CGOff { int o[17]; };

// ---------------------------------------------------------------------------
// Geometry
// ---------------------------------------------------------------------------

__global__ void mace_geom_kernel(const float* __restrict__ vec,
                                 float* __restrict__ ysh, float* __restrict__ rbf)
{
    int e = blockIdx.x * blockDim.x + threadIdx.x;
    if (e >= NEDGE) return;
    float x = vec[3*e+0], y = vec[3*e+1], z = vec[3*e+2];
    float r = sqrtf(x*x + y*y + z*z);
    float inv = 1.0f / (r + 1e-9f);
    float ux = x*inv, uy = y*inv, uz = z*inv;

    const float s3    = 1.7320508075688772f;
    const float s5_2  = 1.1180339887498949f;
    const float s15   = 3.8729833462074170f;
    const float s15_2 = 1.9364916731037085f;
    const float s35_8 = 2.0916500663351889f;
    const float s105  = 10.246950765959598f;
    const float s21_8 = 1.6201851746019651f;
    const float s7_2  = 1.3228756555322954f;
    const float s105_2= 5.1234753829797990f;

    float* Y = ysh + (size_t)e * 16;
    Y[0]  = 1.0f;
    Y[1]  = s3 * uy;
    Y[2]  = s3 * uz;
    Y[3]  = s3 * ux;
    Y[4]  = s15 * ux * uy;
    Y[5]  = s15 * uy * uz;
    Y[6]  = s5_2 * (3.f*uz*uz - 1.f);
    Y[7]  = s15 * ux * uz;
    Y[8]  = s15_2 * (ux*ux - uy*uy);
    Y[9]  = s35_8 * uy * (3.f*ux*ux - uy*uy);
    Y[10] = s105 * ux * uy * uz;
    Y[11] = s21_8 * uy * (5.f*uz*uz - 1.f);
    Y[12] = s7_2 * uz * (5.f*uz*uz - 3.f);
    Y[13] = s21_8 * ux * (5.f*uz*uz - 1.f);
    Y[14] = s105_2 * uz * (ux*ux - uy*uy);
    Y[15] = s35_8 * ux * (ux*ux - 3.f*uy*uy);

    float env = 0.f;
    if (r < 1.f) {
        float r2 = r*r, r3 = r2*r, r6 = r3*r3, r7 = r6*r, r8 = r7*r;
        env = 1.f - 28.f*r6 + 48.f*r7 - 21.f*r8;
    }
    const float sq2 = 1.4142135623730951f;
    const float PI_ = 3.14159265358979323846f;
    float* R = rbf + (size_t)e * 8;
    #pragma unroll
    for (int n = 1; n <= 8; n++)
        R[n-1] = sq2 * sinf(PI_ * (float)n * r) * inv * env;
}

__global__ void mace_init_h_kernel(const int* __restrict__ spec,
                                   const float* __restrict__ embed,
                                   float* __restrict__ h)
{
    int idx = blockIdx.x * blockDim.x + threadIdx.x;
    int n = idx >> 10;
    int t = idx & 1023;
    int f = t >> 4, m = t & 15;
    h[idx] = (m == 0) ? embed[spec[n]*FDIM + f] : 0.f;
}

__global__ void mace_radial_kernel(const float* __restrict__ rbf,
                                   const float* __restrict__ W1,
                                   float* __restrict__ hid)
{
    int idx = blockIdx.x * blockDim.x + threadIdx.x;   // NEDGE*64
    int e = idx >> 6, j = idx & 63;
    float a = 0.f;
    #pragma unroll
    for (int n = 0; n < 8; n++)
        a = fmaf(rbf[(size_t)e*8 + n], W1[n*64 + j], a);
    hid[idx] = a / (1.f + expf(-a));
}

// Repack W2 (fp32): W2r[h][g][f][q] = W2[h][(g*4+q)*64 + f], path 23 = 0 pad.
__global__ void w2_pack_kernel(const float* __restrict__ W2, float* __restrict__ W2r)
{
    int idx = blockIdx.x * blockDim.x + threadIdx.x;   // 64*24*64
    if (idx >= 64*24*64) return;
    int f = idx & 63;
    int p = (idx >> 6) % 24;
    int h = idx / (24*64);
    float v = (p < 23) ? W2[(size_t)h*RWN + p*64 + f] : 0.f;
    int g = p >> 2, q = p & 3;
    W2r[(((size_t)h*6 + g)*64 + f)*4 + q] = v;
}

// ---------------------------------------------------------------------------
// CSR build (receivers -> edge lists)
// ---------------------------------------------------------------------------

__global__ void csr_hist_kernel(const int* __restrict__ recv, int* __restrict__ cnt)
{
    int e = blockIdx.x * blockDim.x + threadIdx.x;
    if (e < NEDGE) atomicAdd(&cnt[recv[e]], 1);
}

__global__ void csr_scan_kernel(const int* __restrict__ cnt,
                                int* __restrict__ off, int* __restrict__ cur)
{
    __shared__ int part[1024];
    int t = threadIdx.x;
    int v0 = cnt[t*4+0], v1 = cnt[t*4+1], v2 = cnt[t*4+2], v3 = cnt[t*4+3];
    int sum = v0 + v1 + v2 + v3;
    part[t] = sum;
    __syncthreads();
    for (int d = 1; d < 1024; d <<= 1) {
        int x = (t >= d) ? part[t-d] : 0;
        __syncthreads();
        part[t] += x;
        __syncthreads();
    }
    int run = part[t] - sum;   // exclusive base
    off[t*4+0] = run; cur[t*4+0] = run; run += v0;
    off[t*4+1] = run; cur[t*4+1] = run; run += v1;
    off[t*4+2] = run; cur[t*4+2] = run; run += v2;
    off[t*4+3] = run; cur[t*4+3] = run; run += v3;
    if (t == 1023) off[4096] = run;
}

__global__ void csr_scatter_kernel(const int* __restrict__ recv,
                                   int* __restrict__ cur, int* __restrict__ eidx)
{
    int e = blockIdx.x * blockDim.x + threadIdx.x;
    if (e < NEDGE) {
        int pos = atomicAdd(&cur[recv[e]], 1);
        eidx[pos] = e;
    }
}

// ---------------------------------------------------------------------------
// Linear kernels
// ---------------------------------------------------------------------------

__global__ void mace_lin_kernel(const float* __restrict__ in,
                                const float* __restrict__ W,
                                const float* __restrict__ add,
                                float* __restrict__ out, float scale)
{
    int n = blockIdx.x;
    int tid = threadIdx.x;                 // 1024 = f*16+m
    __shared__ float s[1024];
    size_t base = (size_t)n * 1024;
    s[tid] = in[base + tid];
    __syncthreads();
    int f = tid >> 4, m = tid & 15;
    int l = (m == 0) ? 0 : (m < 4) ? 1 : (m < 9) ? 2 : 3;
    const float* w = W + l*4096 + f*64;
    float a = 0.f;
    #pragma unroll
    for (int g = 0; g < 64; g++)
        a = fmaf(w[g], s[g*16 + m], a);
    a *= scale;
    if (add) a += add[base + tid];
    out[base + tid] = a;
}

__global__ void mace_lin_sp_kernel(const float* __restrict__ in,
                                   const float* __restrict__ Wsp,
                                   const int* __restrict__ spec,
                                   float* __restrict__ out)
{
    int n = blockIdx.x;
    int tid = threadIdx.x;
    __shared__ float s[1024];
    size_t base = (size_t)n * 1024;
    s[tid] = in[base + tid];
    __syncthreads();
    int f = tid >> 4, m = tid & 15;
    int l = (m == 0) ? 0 : (m < 4) ? 1 : (m < 9) ? 2 : 3;
    const float* w = Wsp + (size_t)spec[n]*4*4096 + l*4096 + f*64;
    float a = 0.f;
    #pragma unroll
    for (int g = 0; g < 64; g++)
        a = fmaf(w[g], s[g*16 + m], a);
    out[base + tid] = a;
}

// ---------------------------------------------------------------------------
// Message gather: one wave per node. Edges processed in rounds of 4; the
// radial weights Rw[e,p,f] are computed in-kernel (registers) from hid and a
// repacked fp32 W2, amortizing W2 reads over 4 edges. No atomics; out is
// written exactly once.
// ---------------------------------------------------------------------------

__global__ __launch_bounds__(64) void mace_gather_kernel(
    const float* __restrict__ h1,            // N*F*16
    const float* __restrict__ ysh,           // E*16
    const float* __restrict__ hid,           // E*64
    const float* __restrict__ W2r,           // [64][6][64][4] fp32 (path-padded)
    const int* __restrict__ senders,
    const int* __restrict__ off,
    const int* __restrict__ eidx,
    const uint32_t* __restrict__ cg_pk,
    const float* __restrict__ cg_c,
    CGOff O,
    float* __restrict__ out)                 // N*F*16
{
    int n = blockIdx.x;
    int f = threadIdx.x;
    __shared__ float sy[16];
    __shared__ float shv[64*17];
    __shared__ float srw[64*25];
    __shared__ float shid4[4*64];
    __shared__ int   sei[8];                 // edge ids [0..3], senders [4..7]

    float acc[16];
    #pragma unroll
    for (int k = 0; k < 16; k++) acc[k] = 0.f;

    int ib = off[n], ie = off[n+1];
    for (int base = ib; base < ie; base += 4) {
        int cnt = ie - base; if (cnt > 4) cnt = 4;
        __syncthreads();
        if (f < 4) {
            int e = eidx[base + ((f < cnt) ? f : 0)];
            sei[f] = e;
            sei[4 + f] = senders[e];
        }
        __syncthreads();
        #pragma unroll
        for (int j = 0; j < 4; j++)
            shid4[j*64 + f] = hid[(size_t)sei[j]*64 + f];
        __syncthreads();

        // rw[j][p] for this lane's f, 4 edges x 24 paths (path 23 is zero pad)
        float rw[4][24];
        #pragma unroll
        for (int j = 0; j < 4; j++)
            #pragma unroll
            for (int p = 0; p < 24; p++) rw[j][p] = 0.f;

        for (int h = 0; h < 64; h++) {
            float hh[4];
            #pragma unroll
            for (int j = 0; j < 4; j++) hh[j] = shid4[j*64 + h];
            #pragma unroll
            for (int g = 0; g < 6; g++) {
                float4 wv = *reinterpret_cast<const float4*>(
                    W2r + (((size_t)h*6 + g)*64 + f)*4);
                #pragma unroll
                for (int j = 0; j < 4; j++) {
                    rw[j][g*4+0] = fmaf(hh[j], wv.x, rw[j][g*4+0]);
                    rw[j][g*4+1] = fmaf(hh[j], wv.y, rw[j][g*4+1]);
                    rw[j][g*4+2] = fmaf(hh[j], wv.z, rw[j][g*4+2]);
                    rw[j][g*4+3] = fmaf(hh[j], wv.w, rw[j][g*4+3]);
                }
            }
        }

        #pragma unroll
        for (int j = 0; j < 4; j++) {
            if (j >= cnt) break;
            int e = sei[j], s = sei[4 + j];
            __syncthreads();
            if (f < 16) sy[f] = ysh[(size_t)e*16 + f];
            const float* hp = h1 + (size_t)s*1024 + f*16;
            #pragma unroll
            for (int k = 0; k < 16; k++) shv[f*17 + k] = hp[k];
            #pragma unroll
            for (int p = 0; p < 23; p++) srw[f*25 + p] = rw[j][p];
            __syncthreads();

            #pragma unroll
            for (int k = 0; k < 16; k++) {
                int t = O.o[k], tend = O.o[k+1];
                float a = 0.f;
                while (t < tend) {
                    uint32_t pk = cg_pk[t];
                    int p = (int)(pk >> 16);
                    float ps = 0.f;
                    for (;;) {
                        int i = pk & 255, jj = (pk >> 8) & 255;
                        ps = fmaf(cg_c[t], shv[f*17 + i] * sy[jj], ps);
                        t++;
                        if (t >= tend) break;
                        pk = cg_pk[t];
                        if ((int)(pk >> 16) != p) break;
                    }
                    a = fmaf(ps, srw[f*25 + p], a);
                }
                acc[k] += a;
            }
        }
    }

    float* dst = out + (size_t)n*1024 + f*16;
    #pragma unroll
    for (int k = 0; k < 16; k++) dst[k] = acc[k];
}

// ---------------------------------------------------------------------------
// Symmetric products
// ---------------------------------------------------------------------------

__global__ void mace_b2_kernel(const float* __restrict__ A,
                               const float* __restrict__ w2base,
                               const int* __restrict__ spec,
                               const uint32_t* __restrict__ cg_pk,
                               const float* __restrict__ cg_c,
                               CGOff O,
                               float* __restrict__ B2)
{
    int n = blockIdx.x;
    int f = threadIdx.x;
    __shared__ float sA[64*17];
    __shared__ float sw[64*25];
    const float* ap = A + (size_t)n*1024 + f*16;
    #pragma unroll
    for (int k = 0; k < 16; k++) sA[f*17 + k] = ap[k];
    int sp = spec[n];
    const float* w2 = w2base + (size_t)sp*(NPATHS*64) + f;
    #pragma unroll
    for (int p = 0; p < NPATHS; p++) sw[f*25 + p] = w2[p*64];
    __syncthreads();

    float* out = B2 + (size_t)n*1024 + f*16;
    #pragma unroll
    for (int k = 0; k < 16; k++) {
        float a = 0.f;
        int t = O.o[k], tend = O.o[k+1];
        while (t < tend) {
            uint32_t pk = cg_pk[t];
            int p = (int)(pk >> 16);
            float ps = 0.f;
            for (;;) {
                int i = pk & 255, j = (pk >> 8) & 255;
                ps = fmaf(cg_c[t], sA[f*17 + i] * sA[f*17 + j], ps);
                t++;
                if (t >= tend) break;
                pk = cg_pk[t];
                if ((int)(pk >> 16) != p) break;
            }
            a = fmaf(ps, sw[f*25 + p], a);
        }
        out[k] = a;
    }
}

__global__ void mace_b3_kernel(const float* __restrict__ A,
                               const float* __restrict__ B2,
                               const float* __restrict__ w3base,
                               const float* __restrict__ w1base,
                               const int* __restrict__ spec,
                               const uint32_t* __restrict__ cg_pk,
                               const float* __restrict__ cg_c,
                               CGOff O,
                               float* __restrict__ out)
{
    int n = blockIdx.x;
    int f = threadIdx.x;
    __shared__ float sA[64*17];
    __shared__ float sB[64*17];
    __shared__ float sw[64*25];
    const float* ap = A  + (size_t)n*1024 + f*16;
    const float* bp = B2 + (size_t)n*1024 + f*16;
    #pragma unroll
    for (int k = 0; k < 16; k++) { sA[f*17 + k] = ap[k]; sB[f*17 + k] = bp[k]; }
    int sp = spec[n];
    const float* w3 = w3base + (size_t)sp*(NPATHS*64) + f;
    #pragma unroll
    for (int p = 0; p < NPATHS; p++) sw[f*25 + p] = w3[p*64];
    float w1 = w1base[sp*64 + f];
    __syncthreads();

    float* op = out + (size_t)n*1024 + f*16;
    #pragma unroll
    for (int k = 0; k < 16; k++) {
        float a = 0.f;
        int t = O.o[k], tend = O.o[k+1];
        while (t < tend) {
            uint32_t pk = cg_pk[t];
            int p = (int)(pk >> 16);
            float ps = 0.f;
            for (;;) {
                int i = pk & 255, j = (pk >> 8) & 255;
                ps = fmaf(cg_c[t], sB[f*17 + i] * sA[f*17 + j], ps);
                t++;
                if (t >= tend) break;
                pk = cg_pk[t];
                if ((int)(pk >> 16) != p) break;
            }
            a = fmaf(ps, sw[f*25 + p], a);
        }
        op[k] = sA[f*17 + k] * w1 + sB[f*17 + k] + a;
    }
}

// ---------------------------------------------------------------------------
// Readouts
// ---------------------------------------------------------------------------

__global__ void mace_readout0_kernel(const float* __restrict__ h,
                                     const float* __restrict__ roW,
                                     float* __restrict__ out)
{
    int n = blockIdx.x;
    int f = threadIdx.x;
    float v = h[(size_t)n*1024 + f*16] * roW[f];
    #pragma unroll
    for (int o = 32; o > 0; o >>= 1) v += __shfl_down(v, o, 64);
    if (f == 0) out[n] = v;
}

__global__ void mace_readout1_kernel(const float* __restrict__ h,
                                     const float* __restrict__ W1,
                                     const float* __restrict__ W2,
                                     float* __restrict__ out)
{
    int n = blockIdx.x;
    int f = threadIdx.x;
    __shared__ float sx[64];
    __shared__ float sz[16];
    sx[f] = h[(size_t)n*1024 + f*16];
    __syncthreads();
    if (f < 16) {
        float z = 0.f;
        #pragma unroll
        for (int g = 0; g < 64; g++) z = fmaf(sx[g], W1[g*16 + f], z);
        z = z / (1.f + expf(-z));
        sz[f] = z * W2[f];
    }
    __syncthreads();
    if (f == 0) {
        float t = 0.f;
        #pragma unroll
        for (int j = 0; j < 16; j++) t += sz[j];
        out[n] += t;
    }
}

// ---------------------------------------------------------------------------
// Host-side CG table (double precision, sorted by (k, p))
// ---------------------------------------------------------------------------

struct HostCG {
    std::vector<uint32_t> upload;  // [MAXCG packed][MAXCG float-bits]
    CGOff off;
    int ncg;
};

static double fct_(int n) { double r = 1.0; for (int i = 2; i <= n; i++) r *= i; return r; }

static double su2_cg_(int j1, int j2, int j3, int m1, int m2, int m3)
{
    if (m1 + m2 != m3) return 0.0;
    int vmin = std::max(std::max(-j1 + j2 + m3, -j1 + m1), 0);
    int vmax = std::min(std::min(j2 + j3 + m1, j3 - j1 + j2), j3 + m3);
    double C = std::sqrt((2.0*j3 + 1.0) * fct_(j3 + j1 - j2) * fct_(j3 - j1 + j2) * fct_(j1 + j2 - j3) / fct_(j1 + j2 + j3 + 1))
             * std::sqrt(fct_(j3 + m3) * fct_(j3 - m3) / (fct_(j1 - m1) * fct_(j1 + m1) * fct_(j2 - m2) * fct_(j2 + m2)));
    double S = 0.0;
    for (int v = vmin; v <= vmax; v++) {
        double t = fct_(j2 + j3 + m1 - v) * fct_(j1 - m1 + v)
                 / (fct_(v) * fct_(j3 - j1 + j2 - v) * fct_(j3 + m3 - v) * fct_(v + j1 - j2 - m3));
        S += (((v + j2 + m2) & 1) ? -1.0 : 1.0) * t;
    }
    return C * S;
}

typedef std::complex<double> cdbl;

static void qmat_(int l, cdbl q[7][7])
{
    for (int a = 0; a < 7; a++) for (int b = 0; b < 7; b++) q[a][b] = cdbl(0, 0);
    double is2 = 1.0 / std::sqrt(2.0);
    for (int m = -l; m < 0; m++) {
        q[l + m][l - m] = cdbl(is2, 0);
        q[l + m][l + m] = cdbl(0, -is2);
    }
    q[l][l] = cdbl(1, 0);
    for (int m = 1; m <= l; m++) {
        double s = (m & 1) ? -1.0 : 1.0;
        q[l + m][l + m] = cdbl(s * is2, 0);
        q[l + m][l - m] = cdbl(0, s * is2);
    }
    cdbl ph = (l == 0) ? cdbl(1, 0) : (l == 1) ? cdbl(0, -1) : (l == 2) ? cdbl(-1, 0) : cdbl(0, 1);
    for (int a = 0; a < 7; a++) for (int b = 0; b < 7; b++) q[a][b] *= ph;
}

struct CGEnt { int p, i, j; float c; };

static HostCG build_cg_()
{
    std::vector<CGEnt> ent_k[16];
    int pidx = 0;
    for (int l1 = 0; l1 <= 3; l1++)
    for (int l2 = 0; l2 <= 3; l2++)
    for (int l3 = std::abs(l1 - l2); l3 <= std::min(3, l1 + l2); l3++) {
        if ((l1 + l2 + l3) & 1) continue;
        int d1 = 2*l1 + 1, d2 = 2*l2 + 1, d3 = 2*l3 + 1;
        cdbl q1[7][7], q2[7][7], q3[7][7];
        qmat_(l1, q1); qmat_(l2, q2); qmat_(l3, q3);
        double Cc[7][7][7];
        for (int i = 0; i < d1; i++)
        for (int k = 0; k < d2; k++)
        for (int m = 0; m < d3; m++)
            Cc[i][k][m] = su2_cg_(l1, l2, l3, i - l1, k - l2, m - l3);
        for (int j = 0; j < d1; j++)
        for (int b = 0; b < d2; b++)
        for (int c = 0; c < d3; c++) {
            cdbl s(0, 0);
            for (int i = 0; i < d1; i++)
            for (int k = 0; k < d2; k++)
            for (int m = 0; m < d3; m++)
                s += q1[i][j] * q2[k][b] * std::conj(q3[m][c]) * Cc[i][k][m];
            float v = (float)s.real();
            if (std::fabs(v) > 1e-10f) {
                int kg = l3*l3 + c;
                ent_k[kg].push_back({pidx, l1*l1 + j, l2*l2 + b, v});
            }
        }
        pidx++;
    }
    HostCG T;
    T.upload.assign(2 * MAXCG, 0u);
    int pos = 0;
    for (int k = 0; k < 16; k++) {
        std::stable_sort(ent_k[k].begin(), ent_k[k].end(),
                         [](const CGEnt& a, const CGEnt& b){ return a.p < b.p; });
        T.off.o[k] = pos;
        for (size_t t = 0; t < ent_k[k].size() && pos < MAXCG; t++) {
            const CGEnt& E2 = ent_k[k][t];
            T.upload[pos] = (uint32_t)E2.i | ((uint32_t)E2.j << 8) | ((uint32_t)E2.p << 16);
            uint32_t bits;
            std::memcpy(&bits, &E2.c, 4);
            T.upload[MAXCG + pos] = bits;
            pos++;
        }
    }
    T.off.o[16] = pos;
    T.ncg = pos;
    return T;
}

// ---------------------------------------------------------------------------
// kernel_launch
// ---------------------------------------------------------------------------

extern "C" void kernel_launch(void* const* d_in, const int* in_sizes, int n_in,
                              void* d_out, int out_size, void* d_ws, size_t ws_size,
                              hipStream_t stream)
{
    const float* vectors = (const float*)d_in[0];
    const int*   senders = (const int*)d_in[1];
    const int*   receivers = (const int*)d_in[2];
    const int*   spec    = (const int*)d_in[3];
    const float* embed_W = (const float*)d_in[4];
    const float* skip_W  = (const float*)d_in[5];
    const float* lin1_W  = (const float*)d_in[6];
    const float* radW1   = (const float*)d_in[7];
    const float* radW2   = (const float*)d_in[8];
    const float* lin2_W  = (const float*)d_in[9];
    const float* skipf_W = (const float*)d_in[10];
    const float* prodW1  = (const float*)d_in[11];
    const float* prodW2  = (const float*)d_in[12];
    const float* prodW3  = (const float*)d_in[13];
    const float* plin_W  = (const float*)d_in[14];
    const float* ro_W    = (const float*)d_in[15];
    const float* mlp_W1  = (const float*)d_in[16];
    const float* mlp_W2  = (const float*)d_in[17];
    float* out = (float*)d_out;

    // workspace layout (floats); total ~103 MB — within the proven-safe
    // round-1 footprint. 16B-aligned sections come before the odd-sized ints.
    float* w   = (float*)d_ws;
    float* ysh = w;                              // E*16
    float* rbf = ysh + (size_t)NEDGE * 16;       // E*8
    float* hid = rbf + (size_t)NEDGE * 8;        // E*64
    float* h   = hid + (size_t)NEDGE * 64;       // N*F*16
    float* t0  = h  + NF16;
    float* t1  = t0 + NF16;
    float* t2  = t1 + NF16;
    float* sc  = t2 + NF16;
    float* w2r = sc + NF16;                      // 98304 floats (16B aligned)
    int* cnt  = (int*)(w2r + W2RN);              // 4096
    int* offs = cnt + 4096;                      // 4097
    int* cur  = offs + 4097;                     // 4096
    int* eidx = cur + 4096;                      // 65536
    uint32_t* d_cgpk = (uint32_t*)(eidx + NEDGE);
    float*    d_cgc  = (float*)(d_cgpk + MAXCG);

    static HostCG T = build_cg_();
    (void)hipMemcpyAsync(d_cgpk, T.upload.data(), T.upload.size() * sizeof(uint32_t),
                         hipMemcpyHostToDevice, stream);

    const float EPS = 0.24253562503633297f;   // 1/sqrt(1+16)

    // CSR build
    (void)hipMemsetAsync(cnt, 0, 4096 * sizeof(int), stream);
    csr_hist_kernel<<<NEDGE/256, 256, 0, stream>>>(receivers, cnt);
    csr_scan_kernel<<<1, 1024, 0, stream>>>(cnt, offs, cur);
    csr_scatter_kernel<<<NEDGE/256, 256, 0, stream>>>(receivers, cur, eidx);

    mace_geom_kernel<<<NEDGE/256, 256, 0, stream>>>(vectors, ysh, rbf);
    mace_init_h_kernel<<<(NNODE*1024)/256, 256, 0, stream>>>(spec, embed_W, h);

    for (int layer = 0; layer < 2; layer++) {
        const float* W1 = radW1 + (size_t)layer * 8 * HDIM;
        const float* W2 = radW2 + (size_t)layer * HDIM * RWN;
        const float* l1W = lin1_W + (size_t)layer * 4 * FDIM * FDIM;
        const float* l2W = lin2_W + (size_t)layer * 4 * FDIM * FDIM;
        const float* plW = plin_W + (size_t)layer * 4 * FDIM * FDIM;
        const float* pw1 = prodW1 + (size_t)layer * NSPEC * FDIM;
        const float* pw2 = prodW2 + (size_t)layer * NSPEC * NPATHS * FDIM;
        const float* pw3 = prodW3 + (size_t)layer * NSPEC * NPATHS * FDIM;

        if (layer == 1) {
            mace_lin_sp_kernel<<<NNODE, 1024, 0, stream>>>(
                h, skip_W + (size_t)1 * NSPEC * 4 * FDIM * FDIM, spec, sc);
        }

        mace_radial_kernel<<<(NEDGE*HDIM)/256, 256, 0, stream>>>(rbf, W1, hid);
        w2_pack_kernel<<<(64*24*64)/256, 256, 0, stream>>>(W2, w2r);
        mace_lin_kernel<<<NNODE, 1024, 0, stream>>>(h, l1W, nullptr, t0, 1.0f);
        mace_gather_kernel<<<NNODE, 64, 0, stream>>>(t0, ysh, hid, w2r, senders,
                                                     offs, eidx, d_cgpk, d_cgc, T.off, t1);
        mace_lin_kernel<<<NNODE, 1024, 0, stream>>>(t1, l2W, nullptr, t2, EPS);

        if (layer == 0) {
            mace_lin_sp_kernel<<<NNODE, 1024, 0, stream>>>(t2, skipf_W, spec, h);
            mace_b2_kernel<<<NNODE, 64, 0, stream>>>(h, pw2, spec, d_cgpk, d_cgc, T.off, t2);
            mace_b3_kernel<<<NNODE, 64, 0, stream>>>(h, t2, pw3, pw1, spec, d_cgpk, d_cgc, T.off, t1);
            mace_lin_kernel<<<NNODE, 1024, 0, stream>>>(t1, plW, nullptr, h, 1.0f);
            mace_readout0_kernel<<<NNODE, 64, 0, stream>>>(h, ro_W, out);
        } else {
            mace_b2_kernel<<<NNODE, 64, 0, stream>>>(t2, pw2, spec, d_cgpk, d_cgc, T.off, h);
            mace_b3_kernel<<<NNODE, 64, 0, stream>>>(t2, h, pw3, pw1, spec, d_cgpk, d_cgc, T.off, t1);
            mace_lin_kernel<<<NNODE, 1024, 0, stream>>>(t1, plW, sc, t0, 1.0f);
            mace_readout1_kernel<<<NNODE, 64, 0, stream>>>(t0, mlp_W1, mlp_W2, out);
        }
    }
}

// Round 5
// 2935.066 us; speedup vs baseline: 2.6585x; 1.7978x over previous
//
#include <hip/hip_runtime.h>
#include <cstdint>
#include <cstring>
#include <cmath>
#include <complex>
#include <vector>
#include <algorithm>

#define NEDGE 65536
#define NNODE 4096
#define FDIM  64
#define LMDIM 16
#define NPATHS 23
#define HDIM  64
#define NSPEC 10
#define MAXCG 1024
#define RWN   (NPATHS*FDIM)                    // 1472
#define NF16  ((size_t)NNODE * FDIM * LMDIM)   // 4,194,304 floats
#define DSZ   439                              // dense D-tensor size
#define MAXDT 512                              // max sparse terms for D assembly
#define STGCAP 17000                           // staged edges capacity per chunk
#define CHUNKN 1024                            // nodes per chunk

struct CGOff { int o[17]; };

__device__ __forceinline__ unsigned short f32_to_bf16_rne(float v)
{
    uint32_t bits;
    __builtin_memcpy(&bits, &v, 4);
    bits += 0x7fffu + ((bits >> 16) & 1u);
    return (unsigned short)(bits >> 16);
}

// ---------------------------------------------------------------------------
// Geometry
// ---------------------------------------------------------------------------

__global__ void mace_geom_kernel(const float* __restrict__ vec,
                                 float* __restrict__ ysh, float* __restrict__ rbf)
{
    int e = blockIdx.x * blockDim.x + threadIdx.x;
    if (e >= NEDGE) return;
    float x = vec[3*e+0], y = vec[3*e+1], z = vec[3*e+2];
    float r = sqrtf(x*x + y*y + z*z);
    float inv = 1.0f / (r + 1e-9f);
    float ux = x*inv, uy = y*inv, uz = z*inv;

    const float s3    = 1.7320508075688772f;
    const float s5_2  = 1.1180339887498949f;
    const float s15   = 3.8729833462074170f;
    const float s15_2 = 1.9364916731037085f;
    const float s35_8 = 2.0916500663351889f;
    const float s105  = 10.246950765959598f;
    const float s21_8 = 1.6201851746019651f;
    const float s7_2  = 1.3228756555322954f;
    const float s105_2= 5.1234753829797990f;

    float* Y = ysh + (size_t)e * 16;
    Y[0]  = 1.0f;
    Y[1]  = s3 * uy;
    Y[2]  = s3 * uz;
    Y[3]  = s3 * ux;
    Y[4]  = s15 * ux * uy;
    Y[5]  = s15 * uy * uz;
    Y[6]  = s5_2 * (3.f*uz*uz - 1.f);
    Y[7]  = s15 * ux * uz;
    Y[8]  = s15_2 * (ux*ux - uy*uy);
    Y[9]  = s35_8 * uy * (3.f*ux*ux - uy*uy);
    Y[10] = s105 * ux * uy * uz;
    Y[11] = s21_8 * uy * (5.f*uz*uz - 1.f);
    Y[12] = s7_2 * uz * (5.f*uz*uz - 3.f);
    Y[13] = s21_8 * ux * (5.f*uz*uz - 1.f);
    Y[14] = s105_2 * uz * (ux*ux - uy*uy);
    Y[15] = s35_8 * ux * (ux*ux - 3.f*uy*uy);

    float env = 0.f;
    if (r < 1.f) {
        float r2 = r*r, r3 = r2*r, r6 = r3*r3, r7 = r6*r, r8 = r7*r;
        env = 1.f - 28.f*r6 + 48.f*r7 - 21.f*r8;
    }
    const float sq2 = 1.4142135623730951f;
    const float PI_ = 3.14159265358979323846f;
    float* R = rbf + (size_t)e * 8;
    #pragma unroll
    for (int n = 1; n <= 8; n++)
        R[n-1] = sq2 * sinf(PI_ * (float)n * r) * inv * env;
}

__global__ void mace_init_h_kernel(const int* __restrict__ spec,
                                   const float* __restrict__ embed,
                                   float* __restrict__ h)
{
    int idx = blockIdx.x * blockDim.x + threadIdx.x;
    int n = idx >> 10;
    int t = idx & 1023;
    int f = t >> 4, m = t & 15;
    h[idx] = (m == 0) ? embed[spec[n]*FDIM + f] : 0.f;
}

__global__ void mace_radial_kernel(const float* __restrict__ rbf,
                                   const float* __restrict__ W1,
                                   float* __restrict__ hid)
{
    int idx = blockIdx.x * blockDim.x + threadIdx.x;   // NEDGE*64
    int e = idx >> 6, j = idx & 63;
    float a = 0.f;
    #pragma unroll
    for (int n = 0; n < 8; n++)
        a = fmaf(rbf[(size_t)e*8 + n], W1[n*64 + j], a);
    hid[idx] = a / (1.f + expf(-a));
}

// ---------------------------------------------------------------------------
// CSR build
// ---------------------------------------------------------------------------

__global__ void csr_hist_kernel(const int* __restrict__ recv, int* __restrict__ cnt)
{
    int e = blockIdx.x * blockDim.x + threadIdx.x;
    if (e < NEDGE) atomicAdd(&cnt[recv[e]], 1);
}

__global__ void csr_scan_kernel(const int* __restrict__ cnt,
                                int* __restrict__ off, int* __restrict__ cur)
{
    __shared__ int part[1024];
    int t = threadIdx.x;
    int v0 = cnt[t*4+0], v1 = cnt[t*4+1], v2 = cnt[t*4+2], v3 = cnt[t*4+3];
    int sum = v0 + v1 + v2 + v3;
    part[t] = sum;
    __syncthreads();
    for (int d = 1; d < 1024; d <<= 1) {
        int x = (t >= d) ? part[t-d] : 0;
        __syncthreads();
        part[t] += x;
        __syncthreads();
    }
    int run = part[t] - sum;
    off[t*4+0] = run; cur[t*4+0] = run; run += v0;
    off[t*4+1] = run; cur[t*4+1] = run; run += v1;
    off[t*4+2] = run; cur[t*4+2] = run; run += v2;
    off[t*4+3] = run; cur[t*4+3] = run; run += v3;
    if (t == 1023) off[4096] = run;
}

__global__ void csr_scatter_kernel(const int* __restrict__ recv,
                                   int* __restrict__ cur, int* __restrict__ eidx)
{
    int e = blockIdx.x * blockDim.x + threadIdx.x;
    if (e < NEDGE) {
        int pos = atomicAdd(&cur[recv[e]], 1);
        eidx[pos] = e;
    }
}

// ---------------------------------------------------------------------------
// Chunked Rw GEMM: stg[i, p*64+f] = sum_h hid[eidx[coff0+i], h] * W2[h, p*64+f]
// (bf16 output, rows in receiver-sorted order)
// ---------------------------------------------------------------------------

__global__ __launch_bounds__(256) void rw_gemm_chunk(
    const float* __restrict__ hid,     // E x 64
    const float* __restrict__ W2,      // 64 x 1472 (layer slice)
    const int* __restrict__ offs,
    const int* __restrict__ eidx,
    int cb,                            // chunk node base
    unsigned short* __restrict__ stg)  // STGCAP x 1472 bf16
{
    int coff0 = offs[cb];
    int count = offs[cb + CHUNKN] - coff0;
    if (count > STGCAP) count = STGCAP;
    int i0 = blockIdx.x * 64;
    if (i0 >= count) return;
    int n0 = blockIdx.y * 64;
    int t = threadIdx.x;

    __shared__ float sa[64][65];   // [h][i]
    __shared__ float sb[64][64];   // [h][n]

    #pragma unroll
    for (int r = 0; r < 16; r++) {
        int idx = r * 256 + t;
        int ii = idx >> 6, hh = idx & 63;
        int row = i0 + ii;
        int g = eidx[coff0 + ((row < count) ? row : 0)];
        sa[hh][ii] = hid[(size_t)g * 64 + hh];
    }
    #pragma unroll
    for (int r = 0; r < 16; r++) {
        int idx = r * 256 + t;
        int hh = idx >> 6, nn = idx & 63;
        sb[hh][nn] = W2[(size_t)hh * RWN + n0 + nn];
    }
    __syncthreads();

    int tx = t & 15, ty = t >> 4;
    float acc[4][4];
    #pragma unroll
    for (int i = 0; i < 4; i++)
        #pragma unroll
        for (int j = 0; j < 4; j++) acc[i][j] = 0.f;

    #pragma unroll 8
    for (int h = 0; h < 64; h++) {
        float a[4], b[4];
        #pragma unroll
        for (int i = 0; i < 4; i++) a[i] = sa[h][ty*4 + i];
        #pragma unroll
        for (int j = 0; j < 4; j++) b[j] = sb[h][tx*4 + j];
        #pragma unroll
        for (int i = 0; i < 4; i++)
            #pragma unroll
            for (int j = 0; j < 4; j++)
                acc[i][j] = fmaf(a[i], b[j], acc[i][j]);
    }

    #pragma unroll
    for (int i = 0; i < 4; i++) {
        int row = i0 + ty*4 + i;
        if (row >= count) continue;
        unsigned short u[4];
        #pragma unroll
        for (int j = 0; j < 4; j++)
            u[j] = f32_to_bf16_rne(acc[i][j]);
        uint2 pack;
        pack.x = (uint32_t)u[0] | ((uint32_t)u[1] << 16);
        pack.y = (uint32_t)u[2] | ((uint32_t)u[3] << 16);
        *reinterpret_cast<uint2*>(&stg[(size_t)row * RWN + n0 + tx*4]) = pack;
    }
}

// ---------------------------------------------------------------------------
// Linear kernels
// ---------------------------------------------------------------------------

__global__ void mace_lin_kernel(const float* __restrict__ in,
                                const float* __restrict__ W,
                                const float* __restrict__ add,
                                float* __restrict__ out, float scale)
{
    int n = blockIdx.x;
    int tid = threadIdx.x;                 // 1024 = f*16+m
    __shared__ float s[1024];
    size_t base = (size_t)n * 1024;
    s[tid] = in[base + tid];
    __syncthreads();
    int f = tid >> 4, m = tid & 15;
    int l = (m == 0) ? 0 : (m < 4) ? 1 : (m < 9) ? 2 : 3;
    const float* w = W + l*4096 + f*64;
    float a = 0.f;
    #pragma unroll
    for (int g = 0; g < 64; g++)
        a = fmaf(w[g], s[g*16 + m], a);
    a *= scale;
    if (add) a += add[base + tid];
    out[base + tid] = a;
}

__global__ void mace_lin_sp_kernel(const float* __restrict__ in,
                                   const float* __restrict__ Wsp,
                                   const int* __restrict__ spec,
                                   float* __restrict__ out)
{
    int n = blockIdx.x;
    int tid = threadIdx.x;
    __shared__ float s[1024];
    size_t base = (size_t)n * 1024;
    s[tid] = in[base + tid];
    __syncthreads();
    int f = tid >> 4, m = tid & 15;
    int l = (m == 0) ? 0 : (m < 4) ? 1 : (m < 9) ? 2 : 3;
    const float* w = Wsp + (size_t)spec[n]*4*4096 + l*4096 + f*64;
    float a = 0.f;
    #pragma unroll
    for (int g = 0; g < 64; g++)
        a = fmaf(w[g], s[g*16 + m], a);
    out[base + tid] = a;
}

// ---------------------------------------------------------------------------
// Dense per-path contraction: acc[k] += rwp * sum_i hv[i] * D[i*(2L3+1)+k]
// All indices compile-time; D reads are LDS broadcasts with immediate offsets.
// ---------------------------------------------------------------------------

template<int L1, int L3>
__device__ __forceinline__ void pathc(const float* __restrict__ Dl,
                                      const float* hv, float rwp, float* acc)
{
    float t[2*L3 + 1];
    #pragma unroll
    for (int k = 0; k <= 2*L3; k++) t[k] = 0.f;
    #pragma unroll
    for (int i = 0; i <= 2*L1; i++) {
        #pragma unroll
        for (int k = 0; k <= 2*L3; k++)
            t[k] = fmaf(hv[i], Dl[i*(2*L3+1) + k], t[k]);
    }
    #pragma unroll
    for (int k = 0; k <= 2*L3; k++) acc[k] = fmaf(t[k], rwp, acc[k]);
}

// ---------------------------------------------------------------------------
// Message gather (chunked): one wave per node. Per edge: hv[16], rw[23] in
// registers; D[439] (uniform) assembled in LDS from sparse CG x Ysh; fully
// unrolled dense contraction. No atomics.
// ---------------------------------------------------------------------------

__global__ void mace_gather_kernel(
    const float* __restrict__ h1,            // N*F*16
    const float* __restrict__ ysh,           // E*16
    const unsigned short* __restrict__ stg,  // STGCAP*1472 bf16 (sorted rows)
    const int* __restrict__ senders,
    const int* __restrict__ offs,
    const int* __restrict__ eidx,
    const int* __restrict__ dstart,          // 440
    const int* __restrict__ dj,              // MAXDT
    const float* __restrict__ dc,            // MAXDT
    int cb,
    float* __restrict__ out)                 // N*F*16
{
    int n = cb + blockIdx.x;
    int f = threadIdx.x;
    __shared__ float syl[16];
    __shared__ float Dl[DSZ];

    float acc[16];
    #pragma unroll
    for (int k = 0; k < 16; k++) acc[k] = 0.f;

    int coff0 = offs[cb];
    int ib = offs[n], ie = offs[n+1];

    for (int idx = ib; idx < ie; idx++) {
        int sidx = idx - coff0;
        if (sidx >= STGCAP) break;
        int e = eidx[idx];
        int s = senders[e];

        // hv registers: the lane's 16 lm-components of h1[sender, f, :]
        float hv[16];
        {
            const float4* hp4 = reinterpret_cast<const float4*>(
                h1 + (size_t)s*1024 + f*16);
            #pragma unroll
            for (int q = 0; q < 4; q++) {
                float4 v = hp4[q];
                hv[q*4+0] = v.x; hv[q*4+1] = v.y;
                hv[q*4+2] = v.z; hv[q*4+3] = v.w;
            }
        }

        // rw registers from staged bf16
        float rw[23];
        {
            const unsigned short* rp = stg + (size_t)sidx*RWN + f;
            #pragma unroll
            for (int p = 0; p < 23; p++) {
                uint32_t b = ((uint32_t)rp[p*64]) << 16;
                __builtin_memcpy(&rw[p], &b, 4);
            }
        }

        __syncthreads();                    // protect syl/Dl from prev iter
        if (f < 16) syl[f] = ysh[(size_t)e*16 + f];
        __syncthreads();

        // D assembly: D[slot] = sum over sparse terms c * Y[j]
        for (int s0 = f; s0 < DSZ; s0 += 64) {
            int t0 = dstart[s0], t1 = dstart[s0+1];
            float d = 0.f;
            for (int t = t0; t < t1; t++)
                d = fmaf(dc[t], syl[dj[t]], d);
            Dl[s0] = d;
        }
        __syncthreads();

        // dense contraction over all 23 paths (l1, l3, hv base, acc base, D base)
        pathc<0,0>(Dl +   0, hv + 0, rw[ 0], acc + 0);
        pathc<0,1>(Dl +   1, hv + 0, rw[ 1], acc + 1);
        pathc<0,2>(Dl +   4, hv + 0, rw[ 2], acc + 4);
        pathc<0,3>(Dl +   9, hv + 0, rw[ 3], acc + 9);
        pathc<1,1>(Dl +  16, hv + 1, rw[ 4], acc + 1);
        pathc<1,0>(Dl +  25, hv + 1, rw[ 5], acc + 0);
        pathc<1,2>(Dl +  28, hv + 1, rw[ 6], acc + 4);
        pathc<1,1>(Dl +  43, hv + 1, rw[ 7], acc + 1);
        pathc<1,3>(Dl +  52, hv + 1, rw[ 8], acc + 9);
        pathc<1,2>(Dl +  73, hv + 1, rw[ 9], acc + 4);
        pathc<2,2>(Dl +  88, hv + 4, rw[10], acc + 4);
        pathc<2,1>(Dl + 113, hv + 4, rw[11], acc + 1);
        pathc<2,3>(Dl + 128, hv + 4, rw[12], acc + 9);
        pathc<2,0>(Dl + 163, hv + 4, rw[13], acc + 0);
        pathc<2,2>(Dl + 168, hv + 4, rw[14], acc + 4);
        pathc<2,1>(Dl + 193, hv + 4, rw[15], acc + 1);
        pathc<2,3>(Dl + 208, hv + 4, rw[16], acc + 9);
        pathc<3,3>(Dl + 243, hv + 9, rw[17], acc + 9);
        pathc<3,2>(Dl + 292, hv + 9, rw[18], acc + 4);
        pathc<3,1>(Dl + 327, hv + 9, rw[19], acc + 1);
        pathc<3,3>(Dl + 348, hv + 9, rw[20], acc + 9);
        pathc<3,0>(Dl + 397, hv + 9, rw[21], acc + 0);
        pathc<3,2>(Dl + 404, hv + 9, rw[22], acc + 4);
    }

    float* dst = out + (size_t)n*1024 + f*16;
    #pragma unroll
    for (int k = 0; k < 16; k++) dst[k] = acc[k];
}

// ---------------------------------------------------------------------------
// Symmetric products (proven round-4 versions, (k,p)-sorted sparse table)
// ---------------------------------------------------------------------------

__global__ void mace_b2_kernel(const float* __restrict__ A,
                               const float* __restrict__ w2base,
                               const int* __restrict__ spec,
                               const uint32_t* __restrict__ cg_pk,
                               const float* __restrict__ cg_c,
                               CGOff O,
                               float* __restrict__ B2)
{
    int n = blockIdx.x;
    int f = threadIdx.x;
    __shared__ float sA[64*17];
    __shared__ float sw[64*25];
    const float* ap = A + (size_t)n*1024 + f*16;
    #pragma unroll
    for (int k = 0; k < 16; k++) sA[f*17 + k] = ap[k];
    int sp = spec[n];
    const float* w2 = w2base + (size_t)sp*(NPATHS*64) + f;
    #pragma unroll
    for (int p = 0; p < NPATHS; p++) sw[f*25 + p] = w2[p*64];
    __syncthreads();

    float* out = B2 + (size_t)n*1024 + f*16;
    #pragma unroll
    for (int k = 0; k < 16; k++) {
        float a = 0.f;
        int t = O.o[k], tend = O.o[k+1];
        while (t < tend) {
            uint32_t pk = cg_pk[t];
            int p = (int)(pk >> 16);
            float ps = 0.f;
            for (;;) {
                int i = pk & 255, j = (pk >> 8) & 255;
                ps = fmaf(cg_c[t], sA[f*17 + i] * sA[f*17 + j], ps);
                t++;
                if (t >= tend) break;
                pk = cg_pk[t];
                if ((int)(pk >> 16) != p) break;
            }
            a = fmaf(ps, sw[f*25 + p], a);
        }
        out[k] = a;
    }
}

__global__ void mace_b3_kernel(const float* __restrict__ A,
                               const float* __restrict__ B2,
                               const float* __restrict__ w3base,
                               const float* __restrict__ w1base,
                               const int* __restrict__ spec,
                               const uint32_t* __restrict__ cg_pk,
                               const float* __restrict__ cg_c,
                               CGOff O,
                               float* __restrict__ out)
{
    int n = blockIdx.x;
    int f = threadIdx.x;
    __shared__ float sA[64*17];
    __shared__ float sB[64*17];
    __shared__ float sw[64*25];
    const float* ap = A  + (size_t)n*1024 + f*16;
    const float* bp = B2 + (size_t)n*1024 + f*16;
    #pragma unroll
    for (int k = 0; k < 16; k++) { sA[f*17 + k] = ap[k]; sB[f*17 + k] = bp[k]; }
    int sp = spec[n];
    const float* w3 = w3base + (size_t)sp*(NPATHS*64) + f;
    #pragma unroll
    for (int p = 0; p < NPATHS; p++) sw[f*25 + p] = w3[p*64];
    float w1 = w1base[sp*64 + f];
    __syncthreads();

    float* op = out + (size_t)n*1024 + f*16;
    #pragma unroll
    for (int k = 0; k < 16; k++) {
        float a = 0.f;
        int t = O.o[k], tend = O.o[k+1];
        while (t < tend) {
            uint32_t pk = cg_pk[t];
            int p = (int)(pk >> 16);
            float ps = 0.f;
            for (;;) {
                int i = pk & 255, j = (pk >> 8) & 255;
                ps = fmaf(cg_c[t], sB[f*17 + i] * sA[f*17 + j], ps);
                t++;
                if (t >= tend) break;
                pk = cg_pk[t];
                if ((int)(pk >> 16) != p) break;
            }
            a = fmaf(ps, sw[f*25 + p], a);
        }
        op[k] = sA[f*17 + k] * w1 + sB[f*17 + k] + a;
    }
}

// ---------------------------------------------------------------------------
// Readouts
// ---------------------------------------------------------------------------

__global__ void mace_readout0_kernel(const float* __restrict__ h,
                                     const float* __restrict__ roW,
                                     float* __restrict__ out)
{
    int n = blockIdx.x;
    int f = threadIdx.x;
    float v = h[(size_t)n*1024 + f*16] * roW[f];
    #pragma unroll
    for (int o = 32; o > 0; o >>= 1) v += __shfl_down(v, o, 64);
    if (f == 0) out[n] = v;
}

__global__ void mace_readout1_kernel(const float* __restrict__ h,
                                     const float* __restrict__ W1,
                                     const float* __restrict__ W2,
                                     float* __restrict__ out)
{
    int n = blockIdx.x;
    int f = threadIdx.x;
    __shared__ float sx[64];
    __shared__ float sz[16];
    sx[f] = h[(size_t)n*1024 + f*16];
    __syncthreads();
    if (f < 16) {
        float z = 0.f;
        #pragma unroll
        for (int g = 0; g < 64; g++) z = fmaf(sx[g], W1[g*16 + f], z);
        z = z / (1.f + expf(-z));
        sz[f] = z * W2[f];
    }
    __syncthreads();
    if (f == 0) {
        float t = 0.f;
        #pragma unroll
        for (int j = 0; j < 16; j++) t += sz[j];
        out[n] += t;
    }
}

// ---------------------------------------------------------------------------
// Host-side CG table construction
// ---------------------------------------------------------------------------

struct HostCG {
    std::vector<uint32_t> upload;  // [pk 1024][c 1024][dstart 440][dj 512][dc 512]
    CGOff off;
};

static double fct_(int n) { double r = 1.0; for (int i = 2; i <= n; i++) r *= i; return r; }

static double su2_cg_(int j1, int j2, int j3, int m1, int m2, int m3)
{
    if (m1 + m2 != m3) return 0.0;
    int vmin = std::max(std::max(-j1 + j2 + m3, -j1 + m1), 0);
    int vmax = std::min(std::min(j2 + j3 + m1, j3 - j1 + j2), j3 + m3);
    double C = std::sqrt((2.0*j3 + 1.0) * fct_(j3 + j1 - j2) * fct_(j3 - j1 + j2) * fct_(j1 + j2 - j3) / fct_(j1 + j2 + j3 + 1))
             * std::sqrt(fct_(j3 + m3) * fct_(j3 - m3) / (fct_(j1 - m1) * fct_(j1 + m1) * fct_(j2 - m2) * fct_(j2 + m2)));
    double S = 0.0;
    for (int v = vmin; v <= vmax; v++) {
        double t = fct_(j2 + j3 + m1 - v) * fct_(j1 - m1 + v)
                 / (fct_(v) * fct_(j3 - j1 + j2 - v) * fct_(j3 + m3 - v) * fct_(v + j1 - j2 - m3));
        S += (((v + j2 + m2) & 1) ? -1.0 : 1.0) * t;
    }
    return C * S;
}

typedef std::complex<double> cdbl;

static void qmat_(int l, cdbl q[7][7])
{
    for (int a = 0; a < 7; a++) for (int b = 0; b < 7; b++) q[a][b] = cdbl(0, 0);
    double is2 = 1.0 / std::sqrt(2.0);
    for (int m = -l; m < 0; m++) {
        q[l + m][l - m] = cdbl(is2, 0);
        q[l + m][l + m] = cdbl(0, -is2);
    }
    q[l][l] = cdbl(1, 0);
    for (int m = 1; m <= l; m++) {
        double s = (m & 1) ? -1.0 : 1.0;
        q[l + m][l + m] = cdbl(s * is2, 0);
        q[l + m][l - m] = cdbl(0, s * is2);
    }
    cdbl ph = (l == 0) ? cdbl(1, 0) : (l == 1) ? cdbl(0, -1) : (l == 2) ? cdbl(-1, 0) : cdbl(0, 1);
    for (int a = 0; a < 7; a++) for (int b = 0; b < 7; b++) q[a][b] *= ph;
}

struct CGEnt { int p, i, j; float c; };
struct DTerm { int slot, j; float c; };

static HostCG build_cg_()
{
    std::vector<CGEnt> ent_k[16];    // (k,p)-sorted sparse table for B2/B3
    std::vector<DTerm> dterms;       // D-assembly terms for gather
    int pidx = 0;
    int dbase = 0;
    for (int l1 = 0; l1 <= 3; l1++)
    for (int l2 = 0; l2 <= 3; l2++)
    for (int l3 = std::abs(l1 - l2); l3 <= std::min(3, l1 + l2); l3++) {
        if ((l1 + l2 + l3) & 1) continue;
        int d1 = 2*l1 + 1, d2 = 2*l2 + 1, d3 = 2*l3 + 1;
        cdbl q1[7][7], q2[7][7], q3[7][7];
        qmat_(l1, q1); qmat_(l2, q2); qmat_(l3, q3);
        double Cc[7][7][7];
        for (int i = 0; i < d1; i++)
        for (int k = 0; k < d2; k++)
        for (int m = 0; m < d3; m++)
            Cc[i][k][m] = su2_cg_(l1, l2, l3, i - l1, k - l2, m - l3);
        for (int j = 0; j < d1; j++)
        for (int b = 0; b < d2; b++)
        for (int c = 0; c < d3; c++) {
            cdbl s(0, 0);
            for (int i = 0; i < d1; i++)
            for (int k = 0; k < d2; k++)
            for (int m = 0; m < d3; m++)
                s += q1[i][j] * q2[k][b] * std::conj(q3[m][c]) * Cc[i][k][m];
            float v = (float)s.real();
            if (std::fabs(v) > 1e-10f) {
                int kg = l3*l3 + c;
                ent_k[kg].push_back({pidx, l1*l1 + j, l2*l2 + b, v});
                dterms.push_back({dbase + j*d3 + c, l2*l2 + b, v});
            }
        }
        dbase += d1 * d3;   // must total DSZ=439 with device-side path bases
        pidx++;
    }

    HostCG T;
    T.upload.assign(2*MAXCG + (DSZ+1) + 2*MAXDT, 0u);
    uint32_t* up_pk = T.upload.data();
    uint32_t* up_c  = up_pk + MAXCG;
    uint32_t* up_ds = up_c + MAXCG;
    uint32_t* up_dj = up_ds + (DSZ + 1);
    uint32_t* up_dc = up_dj + MAXDT;

    int pos = 0;
    for (int k = 0; k < 16; k++) {
        std::stable_sort(ent_k[k].begin(), ent_k[k].end(),
                         [](const CGEnt& a, const CGEnt& b){ return a.p < b.p; });
        T.off.o[k] = pos;
        for (size_t t = 0; t < ent_k[k].size() && pos < MAXCG; t++) {
            const CGEnt& E2 = ent_k[k][t];
            up_pk[pos] = (uint32_t)E2.i | ((uint32_t)E2.j << 8) | ((uint32_t)E2.p << 16);
            std::memcpy(&up_c[pos], &E2.c, 4);
            pos++;
        }
    }
    T.off.o[16] = pos;

    std::stable_sort(dterms.begin(), dterms.end(),
                     [](const DTerm& a, const DTerm& b){ return a.slot < b.slot; });
    int dt = 0;
    for (int s = 0; s <= DSZ; s++) {
        up_ds[s] = (uint32_t)dt;
        while (s < DSZ && dt < (int)dterms.size() && dt < MAXDT &&
               dterms[dt].slot == s) {
            up_dj[dt] = (uint32_t)dterms[dt].j;
            std::memcpy(&up_dc[dt], &dterms[dt].c, 4);
            dt++;
        }
    }
    return T;
}

// ---------------------------------------------------------------------------
// kernel_launch
// ---------------------------------------------------------------------------

extern "C" void kernel_launch(void* const* d_in, const int* in_sizes, int n_in,
                              void* d_out, int out_size, void* d_ws, size_t ws_size,
                              hipStream_t stream)
{
    const float* vectors = (const float*)d_in[0];
    const int*   senders = (const int*)d_in[1];
    const int*   receivers = (const int*)d_in[2];
    const int*   spec    = (const int*)d_in[3];
    const float* embed_W = (const float*)d_in[4];
    const float* skip_W  = (const float*)d_in[5];
    const float* lin1_W  = (const float*)d_in[6];
    const float* radW1   = (const float*)d_in[7];
    const float* radW2   = (const float*)d_in[8];
    const float* lin2_W  = (const float*)d_in[9];
    const float* skipf_W = (const float*)d_in[10];
    const float* prodW1  = (const float*)d_in[11];
    const float* prodW2  = (const float*)d_in[12];
    const float* prodW3  = (const float*)d_in[13];
    const float* plin_W  = (const float*)d_in[14];
    const float* ro_W    = (const float*)d_in[15];
    const float* mlp_W1  = (const float*)d_in[16];
    const float* mlp_W2  = (const float*)d_in[17];
    float* out = (float*)d_out;

    // workspace layout (floats); total ~118.3 MiB.
    // h/t2/ext are dead during the chunked message pass -> staging overlays them.
    float* w   = (float*)d_ws;
    float* ysh = w;                              // E*16
    float* rbf = ysh + (size_t)NEDGE * 16;       // E*8
    float* hid = rbf + (size_t)NEDGE * 8;        // E*64
    float* t0  = hid + (size_t)NEDGE * 64;       // N*F*16 (h1, live in gather)
    float* t1  = t0 + NF16;                      // gather output
    float* sc  = t1 + NF16;                      // skip (layer 1)
    float* h   = sc + NF16;                      // node state / staging lo
    float* t2  = h  + NF16;                      // staging mid
    float* ext = t2 + NF16;                      // staging hi
    unsigned short* stg = (unsigned short*)h;    // 48 MB contiguous staging
    int* cnt  = (int*)(ext + NF16);              // 4096
    int* offs = cnt + 4096;                      // 4097
    int* cur  = offs + 4097;                     // 4096
    int* eidx = cur + 4096;                      // 65536
    uint32_t* d_cgpk   = (uint32_t*)(eidx + NEDGE);
    float*    d_cgc    = (float*)(d_cgpk + MAXCG);
    int*      d_dstart = (int*)(d_cgc + MAXCG);
    int*      d_dj     = d_dstart + (DSZ + 1);
    float*    d_dc     = (float*)(d_dj + MAXDT);

    static HostCG T = build_cg_();
    (void)hipMemcpyAsync(d_cgpk, T.upload.data(), T.upload.size() * sizeof(uint32_t),
                         hipMemcpyHostToDevice, stream);

    const float EPS = 0.24253562503633297f;   // 1/sqrt(1+16)

    // CSR build
    (void)hipMemsetAsync(cnt, 0, 4096 * sizeof(int), stream);
    csr_hist_kernel<<<NEDGE/256, 256, 0, stream>>>(receivers, cnt);
    csr_scan_kernel<<<1, 1024, 0, stream>>>(cnt, offs, cur);
    csr_scatter_kernel<<<NEDGE/256, 256, 0, stream>>>(receivers, cur, eidx);

    mace_geom_kernel<<<NEDGE/256, 256, 0, stream>>>(vectors, ysh, rbf);
    mace_init_h_kernel<<<(NNODE*1024)/256, 256, 0, stream>>>(spec, embed_W, h);

    dim3 ggrid((STGCAP + 63)/64, NPATHS);

    for (int layer = 0; layer < 2; layer++) {
        const float* W1 = radW1 + (size_t)layer * 8 * HDIM;
        const float* W2 = radW2 + (size_t)layer * HDIM * RWN;
        const float* l1W = lin1_W + (size_t)layer * 4 * FDIM * FDIM;
        const float* l2W = lin2_W + (size_t)layer * 4 * FDIM * FDIM;
        const float* plW = plin_W + (size_t)layer * 4 * FDIM * FDIM;
        const float* pw1 = prodW1 + (size_t)layer * NSPEC * FDIM;
        const float* pw2 = prodW2 + (size_t)layer * NSPEC * NPATHS * FDIM;
        const float* pw3 = prodW3 + (size_t)layer * NSPEC * NPATHS * FDIM;

        if (layer == 1) {
            mace_lin_sp_kernel<<<NNODE, 1024, 0, stream>>>(
                h, skip_W + (size_t)1 * NSPEC * 4 * FDIM * FDIM, spec, sc);
        }

        mace_radial_kernel<<<(NEDGE*HDIM)/256, 256, 0, stream>>>(rbf, W1, hid);
        mace_lin_kernel<<<NNODE, 1024, 0, stream>>>(h, l1W, nullptr, t0, 1.0f);
        // h is dead from here until after the chunk loop (staging overlays it)

        for (int c = 0; c < NNODE/CHUNKN; c++) {
            int cb = c * CHUNKN;
            rw_gemm_chunk<<<ggrid, 256, 0, stream>>>(hid, W2, offs, eidx, cb, stg);
            mace_gather_kernel<<<CHUNKN, 64, 0, stream>>>(
                t0, ysh, stg, senders, offs, eidx,
                d_dstart, d_dj, d_dc, cb, t1);
        }

        mace_lin_kernel<<<NNODE, 1024, 0, stream>>>(t1, l2W, nullptr, t2, EPS);

        if (layer == 0) {
            mace_lin_sp_kernel<<<NNODE, 1024, 0, stream>>>(t2, skipf_W, spec, h);
            mace_b2_kernel<<<NNODE, 64, 0, stream>>>(h, pw2, spec, d_cgpk, d_cgc, T.off, t2);
            mace_b3_kernel<<<NNODE, 64, 0, stream>>>(h, t2, pw3, pw1, spec, d_cgpk, d_cgc, T.off, t1);
            mace_lin_kernel<<<NNODE, 1024, 0, stream>>>(t1, plW, nullptr, h, 1.0f);
            mace_readout0_kernel<<<NNODE, 64, 0, stream>>>(h, ro_W, out);
        } else {
            mace_b2_kernel<<<NNODE, 64, 0, stream>>>(t2, pw2, spec, d_cgpk, d_cgc, T.off, h);
            mace_b3_kernel<<<NNODE, 64, 0, stream>>>(t2, h, pw3, pw1, spec, d_cgpk, d_cgc, T.off, t1);
            mace_lin_kernel<<<NNODE, 1024, 0, stream>>>(t1, plW, sc, t0, 1.0f);
            mace_readout1_kernel<<<NNODE, 64, 0, stream>>>(t0, mlp_W1, mlp_W2, out);
        }
    }
}